// Round 6
// baseline (238.971 us; speedup 1.0000x reference)
//
#include <hip/hip_runtime.h>
#include <hip/hip_bf16.h>
#include <cstdint>

#define N_NODES 4096
#define IN_FEAT 256
#define OUT_FEAT 64
#define NHEAD 8
#define LOG2E 1.4426950408889634f

typedef __bf16 bf16x8 __attribute__((ext_vector_type(8)));
typedef float  f32x4  __attribute__((ext_vector_type(4)));

// ws layout (bytes) — total ~15.3 MB (ws >= 38.8 MB proven in r3):
//   h_t  @ 0        : 8*64*4096*2 = 4194304   bf16 [h][feat][node]
//   srcp @ 4194304  : 8*4096*4    = 131072
//   dstp @ 4325376  : 8*4096*4    = 131072
//   Wt   @ 4456448  : 8*64*256*2  = 262144    bf16 [h][col][k]
//   bm2  @ 4718592  : 4096*128*4  = 2097152   bit m%32 of word m/32 = adj!=0
//   numA @ 6815744  : 4096*8*64*4 = 8388608   f32 atomic accumulators
//   denA @ 15204352 : 4096*8*4    = 131072
#define OFF_SRCP 4194304
#define OFF_DSTP 4325376
#define OFF_WT   4456448
#define OFF_BM   4718592
#define OFF_NUMA 6815744
#define OFF_DENA 15204352

// ---------------------------------------------------------------------------
// Pack adj -> bm2[row][128] uint32. Wave per row; lane i reads int4 at
// lane-stride 16 B (fully coalesced, unlike r5's 128 B/lane stream).
// Bits assembled via LDS atomicOr (DS ops are wave-ordered).
// ---------------------------------------------------------------------------
__global__ __launch_bounds__(256) void gat_pack(
    const int* __restrict__ adj, unsigned int* __restrict__ bm2)
{
    __shared__ unsigned int wds[4][128];
    const int wv   = threadIdx.x >> 6;
    const int lane = threadIdx.x & 63;
    const int row  = blockIdx.x * 4 + wv;

    wds[wv][lane]      = 0;
    wds[wv][lane + 64] = 0;
    __syncthreads();

    const int* p = adj + (size_t)row * N_NODES;
    #pragma unroll 4
    for (int k = 0; k < 16; ++k) {
        int4 v = *(const int4*)(p + k * 256 + lane * 4);
        unsigned nib = (v.x ? 1u : 0u) | (v.y ? 2u : 0u)
                     | (v.z ? 4u : 0u) | (v.w ? 8u : 0u);
        int m4 = k * 256 + lane * 4;
        atomicOr(&wds[wv][m4 >> 5], nib << (m4 & 31));
    }
    __syncthreads();
    unsigned int* dst = bm2 + (size_t)row * 128;
    dst[lane]      = wds[wv][lane];
    dst[lane + 64] = wds[wv][lane + 64];
}

// ---------------------------------------------------------------------------
// Prepack: Wt[hd][col][k] = (bf16) W[hd][k][col].
// ---------------------------------------------------------------------------
__global__ __launch_bounds__(256) void gat_prepack(
    const float* __restrict__ W, __bf16* __restrict__ Wt)
{
    int gid = blockIdx.x * 256 + threadIdx.x;   // 0..16383
    int hd  = gid >> 11;
    int rem = gid & 2047;
    int c   = rem >> 5;
    int kg  = rem & 31;
    const float* src = W + ((size_t)hd * IN_FEAT + kg * 8) * OUT_FEAT + c;
    bf16x8 v;
    #pragma unroll
    for (int t = 0; t < 8; ++t) v[t] = (__bf16)src[(size_t)t * OUT_FEAT];
    *(bf16x8*)(Wt + ((size_t)hd * OUT_FEAT + c) * IN_FEAT + kg * 8) = v;
}

static __device__ inline unsigned int pk2(float a, float b) {
    union { __bf16 h[2]; unsigned int u; } t;
    t.h[0] = (__bf16)a; t.h[1] = (__bf16)b; return t.u;
}

// ---------------------------------------------------------------------------
// Phase 1: h = x @ W[h]. x-tile (16 rows x 256) staged coalesced into LDS as
// bf16 (+8 pad -> conflict-free ds_read_b128 fragments). 512 blocks x 256 thr;
// block = (tile, headgroup of 4); wave = one head.
// ---------------------------------------------------------------------------
__global__ __launch_bounds__(256, 4) void gat_phase1(
    const float*  __restrict__ x,      // [4096][256]
    const __bf16* __restrict__ Wt,     // [8][64][256]
    const float*  __restrict__ a,      // [8][128]
    __bf16* __restrict__ h_t,
    float*  __restrict__ srcp,
    float*  __restrict__ dstp)
{
    __shared__ __bf16 xs[16][264];     // pad 8 -> bank stride 132 dw (2-way free)

    const int lane = threadIdx.x & 63;
    const int wv   = threadIdx.x >> 6;
    const int tile = blockIdx.x >> 1;
    const int hd   = (blockIdx.x & 1) * 4 + wv;
    const int r    = lane & 15;
    const int q    = lane >> 4;
    const int nb   = tile * 16;

    // stage x tile: 4096 f32, thread t covers 4x float4 (coalesced)
    #pragma unroll
    for (int c = 0; c < 4; ++c) {
        int idx = c * 1024 + threadIdx.x * 4;
        int row = idx >> 8, col = idx & 255;
        float4 v = *(const float4*)(x + (size_t)(nb + row) * IN_FEAT + col);
        uint2 st = { pk2(v.x, v.y), pk2(v.z, v.w) };
        *(uint2*)(&xs[row][col]) = st;
    }
    __syncthreads();

    const __bf16* Wth = Wt + (size_t)hd * OUT_FEAT * IN_FEAT;
    f32x4 acc[4] = {};   // acc[f][reg] = h[nb+4q+reg][16f + r]

    #pragma unroll 2
    for (int k0 = 0; k0 < IN_FEAT; k0 += 32) {
        bf16x8 af = *(const bf16x8*)(&xs[r][k0 + q * 8]);   // ds_read_b128
        #pragma unroll
        for (int f = 0; f < 4; ++f) {
            bf16x8 bf = *(const bf16x8*)(Wth + (size_t)(16 * f + r) * IN_FEAT + k0 + q * 8);
            acc[f] = __builtin_amdgcn_mfma_f32_16x16x32_bf16(af, bf, acc[f], 0, 0, 0);
        }
    }

    float asv[4], adv[4];
    #pragma unroll
    for (int f = 0; f < 4; ++f) {
        asv[f] = a[hd * 128 + 16 * f + r];
        adv[f] = a[hd * 128 + 64 + 16 * f + r];
    }
    float sp[4], dp[4];
    #pragma unroll
    for (int reg = 0; reg < 4; ++reg) {
        sp[reg] = acc[0][reg] * asv[0] + acc[1][reg] * asv[1]
                + acc[2][reg] * asv[2] + acc[3][reg] * asv[3];
        dp[reg] = acc[0][reg] * adv[0] + acc[1][reg] * adv[1]
                + acc[2][reg] * adv[2] + acc[3][reg] * adv[3];
    }
    #pragma unroll
    for (int m = 1; m <= 8; m <<= 1) {
        #pragma unroll
        for (int reg = 0; reg < 4; ++reg) {
            sp[reg] += __shfl_xor(sp[reg], m);
            dp[reg] += __shfl_xor(dp[reg], m);
        }
    }

    #pragma unroll
    for (int f = 0; f < 4; ++f) {
        uint2 st = { pk2(acc[f][0], acc[f][1]), pk2(acc[f][2], acc[f][3]) };
        *(uint2*)(h_t + (size_t)(hd * OUT_FEAT + 16 * f + r) * N_NODES + nb + 4 * q) = st;
    }

    if (r == 0) {
        #pragma unroll
        for (int reg = 0; reg < 4; ++reg) {
            int row = nb + 4 * q + reg;
            srcp[hd * N_NODES + row] = sp[reg] * LOG2E;
            dstp[hd * N_NODES + row] = dp[reg] * LOG2E;
        }
    }
}

// ---------------------------------------------------------------------------
// Phase 2: grid = 4 chunks x 128 rowblocks (32 rows), 512 thr (wave = head).
// Two-buffer distance-2 software pipeline, loads reload their own buffer in
// place (no mov chain). __launch_bounds__(512,2): 256-VGPR budget so both
// buffers + 40 acc VGPRs stay live (r5 bug: compiler sat at 64 VGPRs).
// ---------------------------------------------------------------------------
struct P2Buf {
    float4 d0, d1;
    bf16x8 b0, b1, b2, b3;
    unsigned int w0, w1;
};

__global__ __launch_bounds__(512, 2) void gat_phase2p(
    const __bf16* __restrict__ h_t,
    const float*  __restrict__ srcp,
    const float*  __restrict__ dstp,
    const unsigned int* __restrict__ bm2,
    float* __restrict__ numA,
    float* __restrict__ denA)
{
    const int lane   = threadIdx.x & 63;
    const int hd     = threadIdx.x >> 6;
    const int r      = lane & 15;
    const int q      = lane >> 4;
    const int q8     = q * 8;
    const int rowblk = blockIdx.x & 127;
    const int chunk  = blockIdx.x >> 7;
    const int n0     = rowblk * 32;
    const int mbase  = chunk * 1024;

    const float   srcv0 = srcp[hd * N_NODES + n0 + r];
    const float   srcv1 = srcp[hd * N_NODES + n0 + 16 + r];
    const float*  dsth  = dstp + (size_t)hd * N_NODES + mbase;
    const __bf16* Vb    = h_t + (size_t)hd * OUT_FEAT * N_NODES + mbase;
    const __bf16* Vh0   = Vb + (size_t)(r)      * N_NODES;
    const __bf16* Vh1   = Vb + (size_t)(16 + r) * N_NODES;
    const __bf16* Vh2   = Vb + (size_t)(32 + r) * N_NODES;
    const __bf16* Vh3   = Vb + (size_t)(48 + r) * N_NODES;
    const unsigned int* bw0p = bm2 + (size_t)(n0 + r)      * 128 + chunk * 32;
    const unsigned int* bw1p = bm2 + (size_t)(n0 + 16 + r) * 128 + chunk * 32;

    f32x4 acc0 = {}, acc1 = {}, acc2 = {}, acc3 = {}, accD0 = {};
    f32x4 acc4 = {}, acc5 = {}, acc6 = {}, acc7 = {}, accD1 = {};
    bf16x8 ones;
    #pragma unroll
    for (int j = 0; j < 8; ++j) ones[j] = (__bf16)1.0f;

    auto loadbuf = [&](P2Buf& B, int it) {
        const int mq = it * 32 + q8;
        B.d0 = *(const float4*)(dsth + mq);
        B.d1 = *(const float4*)(dsth + mq + 4);
        B.b0 = *(const bf16x8*)(Vh0 + mq);
        B.b1 = *(const bf16x8*)(Vh1 + mq);
        B.b2 = *(const bf16x8*)(Vh2 + mq);
        B.b3 = *(const bf16x8*)(Vh3 + mq);
        B.w0 = bw0p[it];
        B.w1 = bw1p[it];
    };
    auto compute = [&](const P2Buf& B) {
        float dv[8] = {B.d0.x, B.d0.y, B.d0.z, B.d0.w,
                       B.d1.x, B.d1.y, B.d1.z, B.d1.w};
        unsigned by0 = B.w0 >> q8;
        unsigned by1 = B.w1 >> q8;
        bf16x8 af0, af1;
        #pragma unroll
        for (int j = 0; j < 8; ++j) {
            float t0 = srcv0 + dv[j];
            float e0 = fmaxf(t0, 0.2f * t0);
            af0[j] = (__bf16)((by0 & (1u << j)) ? exp2f(e0) : 0.0f);
            float t1 = srcv1 + dv[j];
            float e1 = fmaxf(t1, 0.2f * t1);
            af1[j] = (__bf16)((by1 & (1u << j)) ? exp2f(e1) : 0.0f);
        }
        acc0  = __builtin_amdgcn_mfma_f32_16x16x32_bf16(af0, B.b0, acc0,  0, 0, 0);
        acc1  = __builtin_amdgcn_mfma_f32_16x16x32_bf16(af0, B.b1, acc1,  0, 0, 0);
        acc2  = __builtin_amdgcn_mfma_f32_16x16x32_bf16(af0, B.b2, acc2,  0, 0, 0);
        acc3  = __builtin_amdgcn_mfma_f32_16x16x32_bf16(af0, B.b3, acc3,  0, 0, 0);
        accD0 = __builtin_amdgcn_mfma_f32_16x16x32_bf16(af0, ones, accD0, 0, 0, 0);
        acc4  = __builtin_amdgcn_mfma_f32_16x16x32_bf16(af1, B.b0, acc4,  0, 0, 0);
        acc5  = __builtin_amdgcn_mfma_f32_16x16x32_bf16(af1, B.b1, acc5,  0, 0, 0);
        acc6  = __builtin_amdgcn_mfma_f32_16x16x32_bf16(af1, B.b2, acc6,  0, 0, 0);
        acc7  = __builtin_amdgcn_mfma_f32_16x16x32_bf16(af1, B.b3, acc7,  0, 0, 0);
        accD1 = __builtin_amdgcn_mfma_f32_16x16x32_bf16(af1, ones, accD1, 0, 0, 0);
    };

    P2Buf A, B;
    loadbuf(A, 0);
    loadbuf(B, 1);
    for (int it = 0; it < 32; it += 2) {
        compute(A);
        loadbuf(A, (it + 2) & 31);   // wrap on last iters: harmless reload
        compute(B);
        loadbuf(B, (it + 3) & 31);
    }

    #pragma unroll
    for (int reg = 0; reg < 4; ++reg) {
        int row0 = n0 + 4 * q + reg;
        int row1 = row0 + 16;
        atomicAdd(&numA[((size_t)row0 * NHEAD + hd) * 64 +  0 + r], acc0[reg]);
        atomicAdd(&numA[((size_t)row0 * NHEAD + hd) * 64 + 16 + r], acc1[reg]);
        atomicAdd(&numA[((size_t)row0 * NHEAD + hd) * 64 + 32 + r], acc2[reg]);
        atomicAdd(&numA[((size_t)row0 * NHEAD + hd) * 64 + 48 + r], acc3[reg]);
        atomicAdd(&numA[((size_t)row1 * NHEAD + hd) * 64 +  0 + r], acc4[reg]);
        atomicAdd(&numA[((size_t)row1 * NHEAD + hd) * 64 + 16 + r], acc5[reg]);
        atomicAdd(&numA[((size_t)row1 * NHEAD + hd) * 64 + 32 + r], acc6[reg]);
        atomicAdd(&numA[((size_t)row1 * NHEAD + hd) * 64 + 48 + r], acc7[reg]);
        if (r == 0) {
            atomicAdd(&denA[(size_t)row0 * NHEAD + hd], accD0[reg]);
            atomicAdd(&denA[(size_t)row1 * NHEAD + hd], accD1[reg]);
        }
    }
}

// ---------------------------------------------------------------------------
// Combine: divide, mean over heads, ELU. 256 blocks x 512 thr (2 cols/thr).
// ---------------------------------------------------------------------------
__global__ __launch_bounds__(512) void gat_combine(
    const float* __restrict__ numA,
    const float* __restrict__ denA,
    float* __restrict__ out)
{
    int gid = blockIdx.x * 512 + threadIdx.x;   // 0..131071
    int row = gid >> 5;
    int cp  = (gid & 31) * 2;
    float s0 = 0.f, s1 = 0.f;
    #pragma unroll
    for (int h = 0; h < NHEAD; ++h) {
        float2 v = *(const float2*)(numA + ((size_t)row * NHEAD + h) * 64 + cp);
        float inv = 1.f / denA[(size_t)row * NHEAD + h];
        s0 += v.x * inv;
        s1 += v.y * inv;
    }
    s0 *= 0.125f; s1 *= 0.125f;
    float e0 = s0 > 0.f ? s0 : expm1f(s0);
    float e1 = s1 > 0.f ? s1 : expm1f(s1);
    float2 pk = {e0, e1};
    *(float2*)(out + (size_t)row * OUT_FEAT + cp) = pk;
}

// ---------------------------------------------------------------------------
extern "C" void kernel_launch(void* const* d_in, const int* in_sizes, int n_in,
                              void* d_out, int out_size, void* d_ws, size_t ws_size,
                              hipStream_t stream)
{
    const float* x   = (const float*)d_in[0];
    const int*   adj = (const int*)d_in[1];
    const float* W   = (const float*)d_in[2];
    const float* a   = (const float*)d_in[3];
    float* out = (float*)d_out;

    char* ws = (char*)d_ws;
    __bf16*       h_t  = (__bf16*)ws;
    float*        srcp = (float*)(ws + OFF_SRCP);
    float*        dstp = (float*)(ws + OFF_DSTP);
    __bf16*       Wt   = (__bf16*)(ws + OFF_WT);
    unsigned int* bm2  = (unsigned int*)(ws + OFF_BM);
    float*        numA = (float*)(ws + OFF_NUMA);
    float*        denA = (float*)(ws + OFF_DENA);

    hipMemsetAsync(ws + OFF_NUMA, 0, 8388608 + 131072, stream);
    gat_pack   <<<1024, 256, 0, stream>>>(adj, bm2);
    gat_prepack<<<64,   256, 0, stream>>>(W, Wt);
    gat_phase1 <<<512,  256, 0, stream>>>(x, Wt, a, h_t, srcp, dstp);
    gat_phase2p<<<512,  512, 0, stream>>>(h_t, srcp, dstp, bm2, numA, denA);
    gat_combine<<<256,  512, 0, stream>>>(numA, denA, out);
}

// Round 7
// 212.438 us; speedup vs baseline: 1.1249x; 1.1249x over previous
//
#include <hip/hip_runtime.h>
#include <hip/hip_bf16.h>
#include <cstdint>

#define N_NODES 4096
#define IN_FEAT 256
#define OUT_FEAT 64
#define NHEAD 8
#define LOG2E 1.4426950408889634f

typedef __bf16 bf16x8 __attribute__((ext_vector_type(8)));
typedef float  f32x4  __attribute__((ext_vector_type(4)));

// ws layout (bytes):
//   h_t  @ 0        : 8*64*4096*2 = 4194304   bf16 [h][feat][node]
//   srcp @ 4194304  : 8*4096*4    = 131072
//   dstp @ 4325376  : 8*4096*4    = 131072
//   Wt   @ 4456448  : 8*64*256*2  = 262144    bf16 [h][col][k]
//   bm2  @ 4718592  : 4096*128*4  = 2097152   bit m%32 of word m/32 = adj!=0
//   numA @ 6815744  : 4096*8*64*4 = 8388608   f32 atomic accumulators
//   denA @ 15204352 : 4096*8*4    = 131072
#define OFF_SRCP 4194304
#define OFF_DSTP 4325376
#define OFF_WT   4456448
#define OFF_BM   4718592
#define OFF_NUMA 6815744
#define OFF_DENA 15204352

__device__ __forceinline__ void async_copy16(const void* g, void* l) {
    __builtin_amdgcn_global_load_lds(
        (const __attribute__((address_space(1))) void*)g,
        (__attribute__((address_space(3))) void*)l, 16, 0, 0);
}

// ---------------------------------------------------------------------------
// Pack adj -> bm2[row][128] uint32 (blocks <1024), fused prepack of
// Wt[hd][col][k] = bf16 W[hd][k][col] (blocks >=1024; saves a dispatch).
// ---------------------------------------------------------------------------
__global__ __launch_bounds__(256) void gat_pack(
    const int* __restrict__ adj, unsigned int* __restrict__ bm2,
    const float* __restrict__ W, __bf16* __restrict__ Wt)
{
    if (blockIdx.x >= 1024) {   // prepack branch
        int gid = (blockIdx.x - 1024) * 256 + threadIdx.x;   // 0..16383
        int hd  = gid >> 11;
        int rem = gid & 2047;
        int c   = rem >> 5;
        int kg  = rem & 31;
        const float* src = W + ((size_t)hd * IN_FEAT + kg * 8) * OUT_FEAT + c;
        bf16x8 v;
        #pragma unroll
        for (int t = 0; t < 8; ++t) v[t] = (__bf16)src[(size_t)t * OUT_FEAT];
        *(bf16x8*)(Wt + ((size_t)hd * OUT_FEAT + c) * IN_FEAT + kg * 8) = v;
        return;
    }

    __shared__ unsigned int wds[4][128];
    const int wv   = threadIdx.x >> 6;
    const int lane = threadIdx.x & 63;
    const int row  = blockIdx.x * 4 + wv;

    wds[wv][lane]      = 0;
    wds[wv][lane + 64] = 0;
    __syncthreads();

    const int* p = adj + (size_t)row * N_NODES;
    #pragma unroll 4
    for (int k = 0; k < 16; ++k) {
        int4 v = *(const int4*)(p + k * 256 + lane * 4);
        unsigned nib = (v.x ? 1u : 0u) | (v.y ? 2u : 0u)
                     | (v.z ? 4u : 0u) | (v.w ? 8u : 0u);
        int m4 = k * 256 + lane * 4;
        atomicOr(&wds[wv][m4 >> 5], nib << (m4 & 31));
    }
    __syncthreads();
    unsigned int* dst = bm2 + (size_t)row * 128;
    dst[lane]      = wds[wv][lane];
    dst[lane + 64] = wds[wv][lane + 64];
}

static __device__ inline unsigned int pk2(float a, float b) {
    union { __bf16 h[2]; unsigned int u; } t;
    t.h[0] = (__bf16)a; t.h[1] = (__bf16)b; return t.u;
}

// ---------------------------------------------------------------------------
// Phase 1: h = x @ W[h]. x-tile staged coalesced into LDS as bf16.
// 512 blocks x 256 thr; block = (tile, headgroup of 4); wave = one head.
// ---------------------------------------------------------------------------
__global__ __launch_bounds__(256, 4) void gat_phase1(
    const float*  __restrict__ x,      // [4096][256]
    const __bf16* __restrict__ Wt,     // [8][64][256]
    const float*  __restrict__ a,      // [8][128]
    __bf16* __restrict__ h_t,
    float*  __restrict__ srcp,
    float*  __restrict__ dstp)
{
    __shared__ __bf16 xs[16][264];

    const int lane = threadIdx.x & 63;
    const int wv   = threadIdx.x >> 6;
    const int tile = blockIdx.x >> 1;
    const int hd   = (blockIdx.x & 1) * 4 + wv;
    const int r    = lane & 15;
    const int q    = lane >> 4;
    const int nb   = tile * 16;

    #pragma unroll
    for (int c = 0; c < 4; ++c) {
        int idx = c * 1024 + threadIdx.x * 4;
        int row = idx >> 8, col = idx & 255;
        float4 v = *(const float4*)(x + (size_t)(nb + row) * IN_FEAT + col);
        uint2 st = { pk2(v.x, v.y), pk2(v.z, v.w) };
        *(uint2*)(&xs[row][col]) = st;
    }
    __syncthreads();

    const __bf16* Wth = Wt + (size_t)hd * OUT_FEAT * IN_FEAT;
    f32x4 acc[4] = {};

    #pragma unroll 2
    for (int k0 = 0; k0 < IN_FEAT; k0 += 32) {
        bf16x8 af = *(const bf16x8*)(&xs[r][k0 + q * 8]);
        #pragma unroll
        for (int f = 0; f < 4; ++f) {
            bf16x8 bf = *(const bf16x8*)(Wth + (size_t)(16 * f + r) * IN_FEAT + k0 + q * 8);
            acc[f] = __builtin_amdgcn_mfma_f32_16x16x32_bf16(af, bf, acc[f], 0, 0, 0);
        }
    }

    float asv[4], adv[4];
    #pragma unroll
    for (int f = 0; f < 4; ++f) {
        asv[f] = a[hd * 128 + 16 * f + r];
        adv[f] = a[hd * 128 + 64 + 16 * f + r];
    }
    float sp[4], dp[4];
    #pragma unroll
    for (int reg = 0; reg < 4; ++reg) {
        sp[reg] = acc[0][reg] * asv[0] + acc[1][reg] * asv[1]
                + acc[2][reg] * asv[2] + acc[3][reg] * asv[3];
        dp[reg] = acc[0][reg] * adv[0] + acc[1][reg] * adv[1]
                + acc[2][reg] * adv[2] + acc[3][reg] * adv[3];
    }
    #pragma unroll
    for (int m = 1; m <= 8; m <<= 1) {
        #pragma unroll
        for (int reg = 0; reg < 4; ++reg) {
            sp[reg] += __shfl_xor(sp[reg], m);
            dp[reg] += __shfl_xor(dp[reg], m);
        }
    }

    #pragma unroll
    for (int f = 0; f < 4; ++f) {
        uint2 st = { pk2(acc[f][0], acc[f][1]), pk2(acc[f][2], acc[f][3]) };
        *(uint2*)(h_t + (size_t)(hd * OUT_FEAT + 16 * f + r) * N_NODES + nb + 4 * q) = st;
    }

    if (r == 0) {
        #pragma unroll
        for (int reg = 0; reg < 4; ++reg) {
            int row = nb + 4 * q + reg;
            srcp[hd * N_NODES + row] = sp[reg] * LOG2E;
            dstp[hd * N_NODES + row] = dp[reg] * LOG2E;
        }
    }
}

// ---------------------------------------------------------------------------
// Phase 2 (m97 structure): block = (head, rowgroup of 256, chunk of 1024 m).
// All 8 waves SAME head -> V-tile (32m x 64f = 4 KB) is block-shared, staged
// async into double-buffered LDS via global_load_lds(16B); 1 barrier/iter.
// Wave = 32 rows; weight math (exp2 etc.) is the intended VALU floor.
// ---------------------------------------------------------------------------
__global__ __launch_bounds__(512, 4) void gat_phase2p(
    const __bf16* __restrict__ h_t,
    const float*  __restrict__ srcp,
    const float*  __restrict__ dstp,
    const unsigned int* __restrict__ bm2,
    float* __restrict__ numA,
    float* __restrict__ denA)
{
    __shared__ __bf16 Vs[2][64 * 32];   // [buf][feat][m] 4 KB each

    const int lane = threadIdx.x & 63;
    const int wv   = threadIdx.x >> 6;
    const int r    = lane & 15;
    const int q    = lane >> 4;
    const int q8   = q * 8;

    const int hd     = blockIdx.x & 7;
    const int rowgrp = (blockIdx.x >> 3) & 15;
    const int chunk  = blockIdx.x >> 7;
    const int n0     = rowgrp * 256 + wv * 32;
    const int mbase  = chunk * 1024;

    const float   srcv0 = srcp[hd * N_NODES + n0 + r];
    const float   srcv1 = srcp[hd * N_NODES + n0 + 16 + r];
    const float*  dsth  = dstp + (size_t)hd * N_NODES + mbase;
    const unsigned int* bw0p = bm2 + (size_t)(n0 + r)      * 128 + chunk * 32;
    const unsigned int* bw1p = bm2 + (size_t)(n0 + 16 + r) * 128 + chunk * 32;

    // staging: waves 0..3 cover 16 feat-rows each; lane -> (feat, m-oct)
    const __bf16* Vhead = h_t + (size_t)hd * OUT_FEAT * N_NODES + mbase;
    const int sfeat = 16 * wv + (lane >> 2);
    const int sm    = (lane & 3) * 8;
    const __bf16* sbase = Vhead + (size_t)sfeat * N_NODES + sm;

    f32x4 acc0 = {}, acc1 = {}, acc2 = {}, acc3 = {}, accD0 = {};
    f32x4 acc4 = {}, acc5 = {}, acc6 = {}, acc7 = {}, accD1 = {};
    bf16x8 ones;
    #pragma unroll
    for (int j = 0; j < 8; ++j) ones[j] = (__bf16)1.0f;

    // prologue: stage iter 0 into buf 0
    if (wv < 4)
        async_copy16(sbase, &Vs[0][16 * wv * 32]);

    for (int it = 0; it < 32; ++it) {
        const int cur = it & 1;
        __syncthreads();   // drains staged loads for buf[cur]; frees buf[1-cur]

        // async-stage next iter into the other buffer
        if (wv < 4) {
            int nit = (it + 1) & 31;   // wrap: harmless reload on last iter
            async_copy16(sbase + nit * 32, &Vs[1 - cur][16 * wv * 32]);
        }

        // per-lane operands
        float4 d0 = *(const float4*)(dsth + it * 32 + q8);
        float4 d1 = *(const float4*)(dsth + it * 32 + q8 + 4);
        unsigned by0 = bw0p[it] >> q8;
        unsigned by1 = bw1p[it] >> q8;
        float dv[8] = {d0.x, d0.y, d0.z, d0.w, d1.x, d1.y, d1.z, d1.w};

        bf16x8 af0, af1;
        #pragma unroll
        for (int j = 0; j < 8; ++j) {
            float t0 = srcv0 + dv[j];
            float e0 = fmaxf(t0, 0.2f * t0);
            af0[j] = (__bf16)((by0 & (1u << j)) ? exp2f(e0) : 0.0f);
            float t1 = srcv1 + dv[j];
            float e1 = fmaxf(t1, 0.2f * t1);
            af1[j] = (__bf16)((by1 & (1u << j)) ? exp2f(e1) : 0.0f);
        }

        bf16x8 b0 = *(const bf16x8*)(&Vs[cur][(     r) * 32 + q8]);
        bf16x8 b1 = *(const bf16x8*)(&Vs[cur][(16 + r) * 32 + q8]);
        bf16x8 b2 = *(const bf16x8*)(&Vs[cur][(32 + r) * 32 + q8]);
        bf16x8 b3 = *(const bf16x8*)(&Vs[cur][(48 + r) * 32 + q8]);

        acc0  = __builtin_amdgcn_mfma_f32_16x16x32_bf16(af0, b0,   acc0,  0, 0, 0);
        acc1  = __builtin_amdgcn_mfma_f32_16x16x32_bf16(af0, b1,   acc1,  0, 0, 0);
        acc2  = __builtin_amdgcn_mfma_f32_16x16x32_bf16(af0, b2,   acc2,  0, 0, 0);
        acc3  = __builtin_amdgcn_mfma_f32_16x16x32_bf16(af0, b3,   acc3,  0, 0, 0);
        accD0 = __builtin_amdgcn_mfma_f32_16x16x32_bf16(af0, ones, accD0, 0, 0, 0);
        acc4  = __builtin_amdgcn_mfma_f32_16x16x32_bf16(af1, b0,   acc4,  0, 0, 0);
        acc5  = __builtin_amdgcn_mfma_f32_16x16x32_bf16(af1, b1,   acc5,  0, 0, 0);
        acc6  = __builtin_amdgcn_mfma_f32_16x16x32_bf16(af1, b2,   acc6,  0, 0, 0);
        acc7  = __builtin_amdgcn_mfma_f32_16x16x32_bf16(af1, b3,   acc7,  0, 0, 0);
        accD1 = __builtin_amdgcn_mfma_f32_16x16x32_bf16(af1, ones, accD1, 0, 0, 0);
    }

    #pragma unroll
    for (int reg = 0; reg < 4; ++reg) {
        int row0 = n0 + 4 * q + reg;
        int row1 = row0 + 16;
        atomicAdd(&numA[((size_t)row0 * NHEAD + hd) * 64 +  0 + r], acc0[reg]);
        atomicAdd(&numA[((size_t)row0 * NHEAD + hd) * 64 + 16 + r], acc1[reg]);
        atomicAdd(&numA[((size_t)row0 * NHEAD + hd) * 64 + 32 + r], acc2[reg]);
        atomicAdd(&numA[((size_t)row0 * NHEAD + hd) * 64 + 48 + r], acc3[reg]);
        atomicAdd(&numA[((size_t)row1 * NHEAD + hd) * 64 +  0 + r], acc4[reg]);
        atomicAdd(&numA[((size_t)row1 * NHEAD + hd) * 64 + 16 + r], acc5[reg]);
        atomicAdd(&numA[((size_t)row1 * NHEAD + hd) * 64 + 32 + r], acc6[reg]);
        atomicAdd(&numA[((size_t)row1 * NHEAD + hd) * 64 + 48 + r], acc7[reg]);
        if (r == 0) {
            atomicAdd(&denA[(size_t)row0 * NHEAD + hd], accD0[reg]);
            atomicAdd(&denA[(size_t)row1 * NHEAD + hd], accD1[reg]);
        }
    }
}

// ---------------------------------------------------------------------------
// Combine: divide, mean over heads, ELU. 256 blocks x 512 thr (2 cols/thr).
// ---------------------------------------------------------------------------
__global__ __launch_bounds__(512) void gat_combine(
    const float* __restrict__ numA,
    const float* __restrict__ denA,
    float* __restrict__ out)
{
    int gid = blockIdx.x * 512 + threadIdx.x;   // 0..131071
    int row = gid >> 5;
    int cp  = (gid & 31) * 2;
    float s0 = 0.f, s1 = 0.f;
    #pragma unroll
    for (int h = 0; h < NHEAD; ++h) {
        float2 v = *(const float2*)(numA + ((size_t)row * NHEAD + h) * 64 + cp);
        float inv = 1.f / denA[(size_t)row * NHEAD + h];
        s0 += v.x * inv;
        s1 += v.y * inv;
    }
    s0 *= 0.125f; s1 *= 0.125f;
    float e0 = s0 > 0.f ? s0 : expm1f(s0);
    float e1 = s1 > 0.f ? s1 : expm1f(s1);
    float2 pk = {e0, e1};
    *(float2*)(out + (size_t)row * OUT_FEAT + cp) = pk;
}

// ---------------------------------------------------------------------------
extern "C" void kernel_launch(void* const* d_in, const int* in_sizes, int n_in,
                              void* d_out, int out_size, void* d_ws, size_t ws_size,
                              hipStream_t stream)
{
    const float* x   = (const float*)d_in[0];
    const int*   adj = (const int*)d_in[1];
    const float* W   = (const float*)d_in[2];
    const float* a   = (const float*)d_in[3];
    float* out = (float*)d_out;

    char* ws = (char*)d_ws;
    __bf16*       h_t  = (__bf16*)ws;
    float*        srcp = (float*)(ws + OFF_SRCP);
    float*        dstp = (float*)(ws + OFF_DSTP);
    __bf16*       Wt   = (__bf16*)(ws + OFF_WT);
    unsigned int* bm2  = (unsigned int*)(ws + OFF_BM);
    float*        numA = (float*)(ws + OFF_NUMA);
    float*        denA = (float*)(ws + OFF_DENA);

    hipMemsetAsync(ws + OFF_NUMA, 0, 8388608 + 131072, stream);
    gat_pack   <<<1088, 256, 0, stream>>>(adj, bm2, W, Wt);
    gat_phase1 <<<512,  256, 0, stream>>>(x, Wt, a, h_t, srcp, dstp);
    gat_phase2p<<<512,  512, 0, stream>>>(h_t, srcp, dstp, bm2, numA, denA);
    gat_combine<<<256,  512, 0, stream>>>(numA, denA, out);
}

// Round 8
// 197.825 us; speedup vs baseline: 1.2080x; 1.0739x over previous
//
#include <hip/hip_runtime.h>
#include <hip/hip_bf16.h>
#include <cstdint>

#define N_NODES 4096
#define IN_FEAT 256
#define OUT_FEAT 64
#define NHEAD 8
#define LOG2E 1.4426950408889634f

typedef __bf16 bf16x8 __attribute__((ext_vector_type(8)));
typedef float  f32x4  __attribute__((ext_vector_type(4)));

// ws layout (bytes) — total 15,597,568 (< 38.8 MB proven in r3):
//   h_t  @ 0        : 8*64*4096*2 = 4194304   bf16 [h][feat][node]
//   srcE @ 4194304  : 8*4096*8    = 262144    float2 (exp2(t), exp2(0.2t)) per (h,n)
//   dstE @ 4456448  : 8*4096*8    = 262144    float2 per (h,m)
//   Wt   @ 4718592  : 8*64*256*2  = 262144    bf16 [h][col][k]
//   bm2  @ 4980736  : 4096*128*4  = 2097152   bit m%32 of word m/32 = adj!=0
//   numA @ 7077888  : 4096*8*64*4 = 8388608   f32 atomic accumulators
//   denA @ 15466496 : 4096*8*4    = 131072
#define OFF_SRCE 4194304
#define OFF_DSTE 4456448
#define OFF_WT   4718592
#define OFF_BM   4980736
#define OFF_NUMA 7077888
#define OFF_DENA 15466496
#define ZERO_BYTES (8388608 + 131072)

__device__ __forceinline__ void async_copy16(const void* g, void* l) {
    __builtin_amdgcn_global_load_lds(
        (const __attribute__((address_space(1))) void*)g,
        (__attribute__((address_space(3))) void*)l, 16, 0, 0);
}

// ---------------------------------------------------------------------------
// Pack kernel, 3 branches by blockIdx:
//   [0,1024)      adj -> bm2 bitmask
//   [1024,1088)   prepack Wt[hd][col][k] = bf16 W[hd][k][col]
//   [1088,2128)   zero numA/denA (replaces the memset dispatch)
// ---------------------------------------------------------------------------
__global__ __launch_bounds__(256) void gat_pack(
    const int* __restrict__ adj, unsigned int* __restrict__ bm2,
    const float* __restrict__ W, __bf16* __restrict__ Wt,
    float* __restrict__ zeroBase)
{
    if (blockIdx.x >= 1088) {   // zero branch
        size_t off = ((size_t)(blockIdx.x - 1088) * 256 + threadIdx.x) * 8;
        float4 z = {0.f, 0.f, 0.f, 0.f};
        *(float4*)(zeroBase + off)     = z;
        *(float4*)(zeroBase + off + 4) = z;
        return;
    }
    if (blockIdx.x >= 1024) {   // prepack branch
        int gid = (blockIdx.x - 1024) * 256 + threadIdx.x;   // 0..16383
        int hd  = gid >> 11;
        int rem = gid & 2047;
        int c   = rem >> 5;
        int kg  = rem & 31;
        const float* src = W + ((size_t)hd * IN_FEAT + kg * 8) * OUT_FEAT + c;
        bf16x8 v;
        #pragma unroll
        for (int t = 0; t < 8; ++t) v[t] = (__bf16)src[(size_t)t * OUT_FEAT];
        *(bf16x8*)(Wt + ((size_t)hd * OUT_FEAT + c) * IN_FEAT + kg * 8) = v;
        return;
    }

    __shared__ unsigned int wds[4][128];
    const int wv   = threadIdx.x >> 6;
    const int lane = threadIdx.x & 63;
    const int row  = blockIdx.x * 4 + wv;

    wds[wv][lane]      = 0;
    wds[wv][lane + 64] = 0;
    __syncthreads();

    const int* p = adj + (size_t)row * N_NODES;
    #pragma unroll 4
    for (int k = 0; k < 16; ++k) {
        int4 v = *(const int4*)(p + k * 256 + lane * 4);
        unsigned nib = (v.x ? 1u : 0u) | (v.y ? 2u : 0u)
                     | (v.z ? 4u : 0u) | (v.w ? 8u : 0u);
        int m4 = k * 256 + lane * 4;
        atomicOr(&wds[wv][m4 >> 5], nib << (m4 & 31));
    }
    __syncthreads();
    unsigned int* dst = bm2 + (size_t)row * 128;
    dst[lane]      = wds[wv][lane];
    dst[lane + 64] = wds[wv][lane + 64];
}

static __device__ inline unsigned int pk2(float a, float b) {
    union { __bf16 h[2]; unsigned int u; } t;
    t.h[0] = (__bf16)a; t.h[1] = (__bf16)b; return t.u;
}

// ---------------------------------------------------------------------------
// Phase 1: h = x @ W[h]. x-tile staged coalesced into LDS as bf16.
// 512 blocks x 256 thr; block = (tile, headgroup of 4); wave = one head.
// Epilogue now stores FACTORED exponentials:
//   srcE[h][n] = (exp2(L2E*s), exp2(0.2*L2E*s)), dstE likewise.
// ---------------------------------------------------------------------------
__global__ __launch_bounds__(256, 4) void gat_phase1(
    const float*  __restrict__ x,      // [4096][256]
    const __bf16* __restrict__ Wt,     // [8][64][256]
    const float*  __restrict__ a,      // [8][128]
    __bf16* __restrict__ h_t,
    float2* __restrict__ srcE,
    float2* __restrict__ dstE)
{
    __shared__ __bf16 xs[16][264];

    const int lane = threadIdx.x & 63;
    const int wv   = threadIdx.x >> 6;
    const int tile = blockIdx.x >> 1;
    const int hd   = (blockIdx.x & 1) * 4 + wv;
    const int r    = lane & 15;
    const int q    = lane >> 4;
    const int nb   = tile * 16;

    #pragma unroll
    for (int c = 0; c < 4; ++c) {
        int idx = c * 1024 + threadIdx.x * 4;
        int row = idx >> 8, col = idx & 255;
        float4 v = *(const float4*)(x + (size_t)(nb + row) * IN_FEAT + col);
        uint2 st = { pk2(v.x, v.y), pk2(v.z, v.w) };
        *(uint2*)(&xs[row][col]) = st;
    }
    __syncthreads();

    const __bf16* Wth = Wt + (size_t)hd * OUT_FEAT * IN_FEAT;
    f32x4 acc[4] = {};

    #pragma unroll 2
    for (int k0 = 0; k0 < IN_FEAT; k0 += 32) {
        bf16x8 af = *(const bf16x8*)(&xs[r][k0 + q * 8]);
        #pragma unroll
        for (int f = 0; f < 4; ++f) {
            bf16x8 bf = *(const bf16x8*)(Wth + (size_t)(16 * f + r) * IN_FEAT + k0 + q * 8);
            acc[f] = __builtin_amdgcn_mfma_f32_16x16x32_bf16(af, bf, acc[f], 0, 0, 0);
        }
    }

    float asv[4], adv[4];
    #pragma unroll
    for (int f = 0; f < 4; ++f) {
        asv[f] = a[hd * 128 + 16 * f + r];
        adv[f] = a[hd * 128 + 64 + 16 * f + r];
    }
    float sp[4], dp[4];
    #pragma unroll
    for (int reg = 0; reg < 4; ++reg) {
        sp[reg] = acc[0][reg] * asv[0] + acc[1][reg] * asv[1]
                + acc[2][reg] * asv[2] + acc[3][reg] * asv[3];
        dp[reg] = acc[0][reg] * adv[0] + acc[1][reg] * adv[1]
                + acc[2][reg] * adv[2] + acc[3][reg] * adv[3];
    }
    #pragma unroll
    for (int m = 1; m <= 8; m <<= 1) {
        #pragma unroll
        for (int reg = 0; reg < 4; ++reg) {
            sp[reg] += __shfl_xor(sp[reg], m);
            dp[reg] += __shfl_xor(dp[reg], m);
        }
    }

    #pragma unroll
    for (int f = 0; f < 4; ++f) {
        uint2 st = { pk2(acc[f][0], acc[f][1]), pk2(acc[f][2], acc[f][3]) };
        *(uint2*)(h_t + (size_t)(hd * OUT_FEAT + 16 * f + r) * N_NODES + nb + 4 * q) = st;
    }

    if (r == 0) {
        #pragma unroll
        for (int reg = 0; reg < 4; ++reg) {
            int row = nb + 4 * q + reg;
            float s = sp[reg] * LOG2E;
            float d = dp[reg] * LOG2E;
            srcE[hd * N_NODES + row] = make_float2(exp2f(s), exp2f(0.2f * s));
            dstE[hd * N_NODES + row] = make_float2(exp2f(d), exp2f(0.2f * d));
        }
    }
}

// ---------------------------------------------------------------------------
// Phase 2 (m97 structure): block = (head, rowgroup of 256, chunk of 1024 m).
// V-tile (32m x 64f) block-shared in double-buffered LDS via global_load_lds.
// Weight via FACTORED exp2:  w = mask ? max(E1s*E1d, E5s*E5d) : 0
// (exp2 is monotone: exp2(max(t,.2t)) = max(exp2 t, exp2 .2t); both factor
//  into per-node terms).  2 mul + max + cndmask per weight — no exp2 in loop.
// ---------------------------------------------------------------------------
__global__ __launch_bounds__(512, 4) void gat_phase2p(
    const __bf16* __restrict__ h_t,
    const float2* __restrict__ srcE,
    const float2* __restrict__ dstE,
    const unsigned int* __restrict__ bm2,
    float* __restrict__ numA,
    float* __restrict__ denA)
{
    __shared__ __bf16 Vs[2][64 * 32];   // [buf][feat][m] 4 KB each

    const int lane = threadIdx.x & 63;
    const int wv   = threadIdx.x >> 6;
    const int r    = lane & 15;
    const int q    = lane >> 4;
    const int q8   = q * 8;

    const int hd     = blockIdx.x & 7;
    const int rowgrp = (blockIdx.x >> 3) & 15;
    const int chunk  = blockIdx.x >> 7;
    const int n0     = rowgrp * 256 + wv * 32;
    const int mbase  = chunk * 1024;

    const float2  se0   = srcE[hd * N_NODES + n0 + r];
    const float2  se1   = srcE[hd * N_NODES + n0 + 16 + r];
    const float2* deh   = dstE + (size_t)hd * N_NODES + mbase;
    const unsigned int* bw0p = bm2 + (size_t)(n0 + r)      * 128 + chunk * 32;
    const unsigned int* bw1p = bm2 + (size_t)(n0 + 16 + r) * 128 + chunk * 32;

    // staging: waves 0..3 cover 16 feat-rows each; lane -> (feat, m-oct)
    const __bf16* Vhead = h_t + (size_t)hd * OUT_FEAT * N_NODES + mbase;
    const int sfeat = 16 * wv + (lane >> 2);
    const int sm    = (lane & 3) * 8;
    const __bf16* sbase = Vhead + (size_t)sfeat * N_NODES + sm;

    f32x4 acc0 = {}, acc1 = {}, acc2 = {}, acc3 = {}, accD0 = {};
    f32x4 acc4 = {}, acc5 = {}, acc6 = {}, acc7 = {}, accD1 = {};
    bf16x8 ones;
    #pragma unroll
    for (int j = 0; j < 8; ++j) ones[j] = (__bf16)1.0f;

    if (wv < 4)
        async_copy16(sbase, &Vs[0][16 * wv * 32]);

    for (int it = 0; it < 32; ++it) {
        const int cur = it & 1;
        __syncthreads();

        if (wv < 4) {
            int nit = (it + 1) & 31;
            async_copy16(sbase + nit * 32, &Vs[1 - cur][16 * wv * 32]);
        }

        // per-lane operands: 8 (E1d,E5d) pairs packed as 4 float4
        const float4* ep = (const float4*)(deh + it * 32 + q8);
        float4 e0 = ep[0], e1 = ep[1], e2 = ep[2], e3 = ep[3];
        float ed1[8] = {e0.x, e0.z, e1.x, e1.z, e2.x, e2.z, e3.x, e3.z};
        float ed5[8] = {e0.y, e0.w, e1.y, e1.w, e2.y, e2.w, e3.y, e3.w};
        unsigned by0 = bw0p[it] >> q8;
        unsigned by1 = bw1p[it] >> q8;

        bf16x8 af0, af1;
        #pragma unroll
        for (int j = 0; j < 8; ++j) {
            float w0 = fmaxf(se0.x * ed1[j], se0.y * ed5[j]);
            af0[j] = (__bf16)((by0 & (1u << j)) ? w0 : 0.0f);
            float w1 = fmaxf(se1.x * ed1[j], se1.y * ed5[j]);
            af1[j] = (__bf16)((by1 & (1u << j)) ? w1 : 0.0f);
        }

        bf16x8 b0 = *(const bf16x8*)(&Vs[cur][(     r) * 32 + q8]);
        bf16x8 b1 = *(const bf16x8*)(&Vs[cur][(16 + r) * 32 + q8]);
        bf16x8 b2 = *(const bf16x8*)(&Vs[cur][(32 + r) * 32 + q8]);
        bf16x8 b3 = *(const bf16x8*)(&Vs[cur][(48 + r) * 32 + q8]);

        acc0  = __builtin_amdgcn_mfma_f32_16x16x32_bf16(af0, b0,   acc0,  0, 0, 0);
        acc1  = __builtin_amdgcn_mfma_f32_16x16x32_bf16(af0, b1,   acc1,  0, 0, 0);
        acc2  = __builtin_amdgcn_mfma_f32_16x16x32_bf16(af0, b2,   acc2,  0, 0, 0);
        acc3  = __builtin_amdgcn_mfma_f32_16x16x32_bf16(af0, b3,   acc3,  0, 0, 0);
        accD0 = __builtin_amdgcn_mfma_f32_16x16x32_bf16(af0, ones, accD0, 0, 0, 0);
        acc4  = __builtin_amdgcn_mfma_f32_16x16x32_bf16(af1, b0,   acc4,  0, 0, 0);
        acc5  = __builtin_amdgcn_mfma_f32_16x16x32_bf16(af1, b1,   acc5,  0, 0, 0);
        acc6  = __builtin_amdgcn_mfma_f32_16x16x32_bf16(af1, b2,   acc6,  0, 0, 0);
        acc7  = __builtin_amdgcn_mfma_f32_16x16x32_bf16(af1, b3,   acc7,  0, 0, 0);
        accD1 = __builtin_amdgcn_mfma_f32_16x16x32_bf16(af1, ones, accD1, 0, 0, 0);
    }

    #pragma unroll
    for (int reg = 0; reg < 4; ++reg) {
        int row0 = n0 + 4 * q + reg;
        int row1 = row0 + 16;
        atomicAdd(&numA[((size_t)row0 * NHEAD + hd) * 64 +  0 + r], acc0[reg]);
        atomicAdd(&numA[((size_t)row0 * NHEAD + hd) * 64 + 16 + r], acc1[reg]);
        atomicAdd(&numA[((size_t)row0 * NHEAD + hd) * 64 + 32 + r], acc2[reg]);
        atomicAdd(&numA[((size_t)row0 * NHEAD + hd) * 64 + 48 + r], acc3[reg]);
        atomicAdd(&numA[((size_t)row1 * NHEAD + hd) * 64 +  0 + r], acc4[reg]);
        atomicAdd(&numA[((size_t)row1 * NHEAD + hd) * 64 + 16 + r], acc5[reg]);
        atomicAdd(&numA[((size_t)row1 * NHEAD + hd) * 64 + 32 + r], acc6[reg]);
        atomicAdd(&numA[((size_t)row1 * NHEAD + hd) * 64 + 48 + r], acc7[reg]);
        if (r == 0) {
            atomicAdd(&denA[(size_t)row0 * NHEAD + hd], accD0[reg]);
            atomicAdd(&denA[(size_t)row1 * NHEAD + hd], accD1[reg]);
        }
    }
}

// ---------------------------------------------------------------------------
// Combine: divide, mean over heads, ELU. 256 blocks x 512 thr (2 cols/thr).
// ---------------------------------------------------------------------------
__global__ __launch_bounds__(512) void gat_combine(
    const float* __restrict__ numA,
    const float* __restrict__ denA,
    float* __restrict__ out)
{
    int gid = blockIdx.x * 512 + threadIdx.x;   // 0..131071
    int row = gid >> 5;
    int cp  = (gid & 31) * 2;
    float s0 = 0.f, s1 = 0.f;
    #pragma unroll
    for (int h = 0; h < NHEAD; ++h) {
        float2 v = *(const float2*)(numA + ((size_t)row * NHEAD + h) * 64 + cp);
        float inv = 1.f / denA[(size_t)row * NHEAD + h];
        s0 += v.x * inv;
        s1 += v.y * inv;
    }
    s0 *= 0.125f; s1 *= 0.125f;
    float e0 = s0 > 0.f ? s0 : expm1f(s0);
    float e1 = s1 > 0.f ? s1 : expm1f(s1);
    float2 pk = {e0, e1};
    *(float2*)(out + (size_t)row * OUT_FEAT + cp) = pk;
}

// ---------------------------------------------------------------------------
extern "C" void kernel_launch(void* const* d_in, const int* in_sizes, int n_in,
                              void* d_out, int out_size, void* d_ws, size_t ws_size,
                              hipStream_t stream)
{
    const float* x   = (const float*)d_in[0];
    const int*   adj = (const int*)d_in[1];
    const float* W   = (const float*)d_in[2];
    const float* a   = (const float*)d_in[3];
    float* out = (float*)d_out;

    char* ws = (char*)d_ws;
    __bf16*       h_t  = (__bf16*)ws;
    float2*       srcE = (float2*)(ws + OFF_SRCE);
    float2*       dstE = (float2*)(ws + OFF_DSTE);
    __bf16*       Wt   = (__bf16*)(ws + OFF_WT);
    unsigned int* bm2  = (unsigned int*)(ws + OFF_BM);
    float*        numA = (float*)(ws + OFF_NUMA);
    float*        denA = (float*)(ws + OFF_DENA);

    gat_pack   <<<2128, 256, 0, stream>>>(adj, bm2, W, Wt, numA);
    gat_phase1 <<<512,  256, 0, stream>>>(x, Wt, a, h_t, srcE, dstE);
    gat_phase2p<<<512,  512, 0, stream>>>(h_t, srcE, dstE, bm2, numA, denA);
    gat_combine<<<256,  512, 0, stream>>>(numA, denA, out);
}

// Round 10
// 189.459 us; speedup vs baseline: 1.2613x; 1.0442x over previous
//
#include <hip/hip_runtime.h>
#include <hip/hip_fp16.h>
#include <cstdint>

#define N_NODES 4096
#define IN_FEAT 256
#define OUT_FEAT 64
#define NHEAD 8
#define LOG2E 1.4426950408889634f

typedef _Float16 f16;
typedef f16   f16x2 __attribute__((ext_vector_type(2)));
typedef f16   f16x8 __attribute__((ext_vector_type(8)));
typedef float f32x4 __attribute__((ext_vector_type(4)));

// ws layout (bytes) — total 30,015,488 (< 38.8 MB proven in r3):
//   h_t   @ 0        : 8*64*4096*2 = 4194304   f16 [h][feat][node]
//   srcPK @ 4194304  : 8*4096*4    = 131072    dword {E1s,E5s} f16 pair per (h,n)
//   dstE1 @ 4325376  : 8*4096*2    = 65536     f16 exp2(t_d) per (h,m)
//   dstE5 @ 4390912  : 8*4096*2    = 65536     f16 exp2(0.2 t_d)
//   Wt    @ 4456448  : 8*64*256*2  = 262144    f16 [h][col][k]
//   emask @ 4718592  : 4096*4096   = 16777216  byte 0xFF/0x00 = adj!=0
//   numA  @ 21495808 : 4096*8*64*4 = 8388608   f32 atomic accumulators
//   denA  @ 29884416 : 4096*8*4    = 131072
#define OFF_SRCPK 4194304
#define OFF_DSTE1 4325376
#define OFF_DSTE5 4390912
#define OFF_WT    4456448
#define OFF_EM    4718592
#define OFF_NUMA  21495808ULL
#define OFF_DENA  29884416ULL

union HU { unsigned u; f16x2 h; };
union A8 { f16x8 v; unsigned u[4]; };

__device__ __forceinline__ void async_copy16(const void* g, void* l) {
    __builtin_amdgcn_global_load_lds(
        (const __attribute__((address_space(1))) void*)g,
        (__attribute__((address_space(3))) void*)l, 16, 0, 0);
}

static __device__ inline unsigned pkh2(float a, float b) {
    union { f16 h[2]; unsigned u; } t;
    t.h[0] = (f16)a; t.h[1] = (f16)b; return t.u;
}

// ---------------------------------------------------------------------------
// Pack kernel, 3 branches by blockIdx:
//   [0,1024)      adj -> emask bytes (elementwise, fully coalesced, no atomics)
//   [1024,1088)   prepack Wt[hd][col][k] = f16 W[hd][k][col]
//   [1088,2128)   zero numA/denA
// ---------------------------------------------------------------------------
__global__ __launch_bounds__(256) void gat_pack(
    const int* __restrict__ adj, unsigned* __restrict__ em32,
    const float* __restrict__ W, f16* __restrict__ Wt,
    float* __restrict__ zeroBase)
{
    if (blockIdx.x >= 1088) {   // zero branch: 1040 blocks x 2048 floats
        size_t off = ((size_t)(blockIdx.x - 1088) * 256 + threadIdx.x) * 8;
        float4 z = {0.f, 0.f, 0.f, 0.f};
        *(float4*)(zeroBase + off)     = z;
        *(float4*)(zeroBase + off + 4) = z;
        return;
    }
    if (blockIdx.x >= 1024) {   // prepack branch
        int gid = (blockIdx.x - 1024) * 256 + threadIdx.x;   // 0..16383
        int hd  = gid >> 11;
        int rem = gid & 2047;
        int c   = rem >> 5;
        int kg  = rem & 31;
        const float* src = W + ((size_t)hd * IN_FEAT + kg * 8) * OUT_FEAT + c;
        f16x8 v;
        #pragma unroll
        for (int t = 0; t < 8; ++t) v[t] = (f16)src[(size_t)t * OUT_FEAT];
        *(f16x8*)(Wt + ((size_t)hd * OUT_FEAT + c) * IN_FEAT + kg * 8) = v;
        return;
    }

    // emask branch: wave per row, 16 steps of int4->4 mask bytes (1 dword)
    const int wv   = threadIdx.x >> 6;
    const int lane = threadIdx.x & 63;
    const int row  = blockIdx.x * 4 + wv;
    const int* p   = adj + (size_t)row * N_NODES;
    unsigned* dst  = em32 + (size_t)row * (N_NODES / 4);
    #pragma unroll 4
    for (int s = 0; s < 16; ++s) {
        int4 v = *(const int4*)(p + s * 256 + lane * 4);
        unsigned d = (v.x ? 0x000000FFu : 0u) | (v.y ? 0x0000FF00u : 0u)
                   | (v.z ? 0x00FF0000u : 0u) | (v.w ? 0xFF000000u : 0u);
        dst[s * 64 + lane] = d;
    }
}

// ---------------------------------------------------------------------------
// Phase 1: h = x @ W[h] (f16 MFMA). Epilogue stores factored exponentials:
//   srcPK[h][n] = packed f16 {exp2(L2E*s), exp2(0.2*L2E*s)}
//   dstE1/dstE5[h][m] = f16 exp2(L2E*d) / exp2(0.2*L2E*d)
// 512 blocks x 256 thr; block = (tile, headgroup of 4); wave = one head.
// ---------------------------------------------------------------------------
__global__ __launch_bounds__(256, 4) void gat_phase1(
    const float* __restrict__ x,      // [4096][256]
    const f16*   __restrict__ Wt,     // [8][64][256]
    const float* __restrict__ a,      // [8][128]
    f16*      __restrict__ h_t,
    unsigned* __restrict__ srcPK,
    f16*      __restrict__ dstE1,
    f16*      __restrict__ dstE5)
{
    __shared__ f16 xs[16][264];

    const int lane = threadIdx.x & 63;
    const int wv   = threadIdx.x >> 6;
    const int tile = blockIdx.x >> 1;
    const int hd   = (blockIdx.x & 1) * 4 + wv;
    const int r    = lane & 15;
    const int q    = lane >> 4;
    const int nb   = tile * 16;

    #pragma unroll
    for (int c = 0; c < 4; ++c) {
        int idx = c * 1024 + threadIdx.x * 4;
        int row = idx >> 8, col = idx & 255;
        float4 v = *(const float4*)(x + (size_t)(nb + row) * IN_FEAT + col);
        uint2 st = { pkh2(v.x, v.y), pkh2(v.z, v.w) };
        *(uint2*)(&xs[row][col]) = st;
    }
    __syncthreads();

    const f16* Wth = Wt + (size_t)hd * OUT_FEAT * IN_FEAT;
    f32x4 acc[4] = {};

    #pragma unroll 2
    for (int k0 = 0; k0 < IN_FEAT; k0 += 32) {
        f16x8 af = *(const f16x8*)(&xs[r][k0 + q * 8]);
        #pragma unroll
        for (int f = 0; f < 4; ++f) {
            f16x8 bf = *(const f16x8*)(Wth + (size_t)(16 * f + r) * IN_FEAT + k0 + q * 8);
            acc[f] = __builtin_amdgcn_mfma_f32_16x16x32_f16(af, bf, acc[f], 0, 0, 0);
        }
    }

    float asv[4], adv[4];
    #pragma unroll
    for (int f = 0; f < 4; ++f) {
        asv[f] = a[hd * 128 + 16 * f + r];
        adv[f] = a[hd * 128 + 64 + 16 * f + r];
    }
    float sp[4], dp[4];
    #pragma unroll
    for (int reg = 0; reg < 4; ++reg) {
        sp[reg] = acc[0][reg] * asv[0] + acc[1][reg] * asv[1]
                + acc[2][reg] * asv[2] + acc[3][reg] * asv[3];
        dp[reg] = acc[0][reg] * adv[0] + acc[1][reg] * adv[1]
                + acc[2][reg] * adv[2] + acc[3][reg] * adv[3];
    }
    #pragma unroll
    for (int m = 1; m <= 8; m <<= 1) {
        #pragma unroll
        for (int reg = 0; reg < 4; ++reg) {
            sp[reg] += __shfl_xor(sp[reg], m);
            dp[reg] += __shfl_xor(dp[reg], m);
        }
    }

    #pragma unroll
    for (int f = 0; f < 4; ++f) {
        uint2 st = { pkh2(acc[f][0], acc[f][1]), pkh2(acc[f][2], acc[f][3]) };
        *(uint2*)(h_t + (size_t)(hd * OUT_FEAT + 16 * f + r) * N_NODES + nb + 4 * q) = st;
    }

    if (r == 0) {
        #pragma unroll
        for (int reg = 0; reg < 4; ++reg) {
            int row = nb + 4 * q + reg;
            float s = sp[reg] * LOG2E;
            float d = dp[reg] * LOG2E;
            srcPK[hd * N_NODES + row] = pkh2(exp2f(s), exp2f(0.2f * s));
            dstE1[hd * N_NODES + row] = (f16)exp2f(d);
            dstE5[hd * N_NODES + row] = (f16)exp2f(0.2f * d);
        }
    }
}

// ---------------------------------------------------------------------------
// Phase 2: grid = 8 heads x 32 rowgrps(128 rows) x 4 chunks = 1024 blocks,
// 256 thr (4 waves, wave = 32 rows). V-tile (32m x 64f f16, 4 KB) block-shared
// in double-buffered LDS via global_load_lds. 4 blocks/CU -> 4 independent
// barrier domains. Weights: packed f16 via native clang vector ops
// (v_pk_mul_f16 / v_pk_max_f16) + byte-expanded AND mask (v_perm).
// ~4 VALU per 2 weights.
// ---------------------------------------------------------------------------
__global__ __launch_bounds__(256, 4) void gat_phase2p(
    const f16* __restrict__ h_t,
    const unsigned* __restrict__ srcPK,
    const f16* __restrict__ dstE1,
    const f16* __restrict__ dstE5,
    const unsigned char* __restrict__ emask8,
    float* __restrict__ numA,
    float* __restrict__ denA)
{
    __shared__ f16 Vs[2][64 * 32];   // [buf][feat][m] 4 KB each

    const int lane = threadIdx.x & 63;
    const int wv   = threadIdx.x >> 6;     // 0..3
    const int r    = lane & 15;
    const int q    = lane >> 4;
    const int q8   = q * 8;

    const int hd     = blockIdx.x & 7;
    const int rowgrp = (blockIdx.x >> 3) & 31;
    const int chunk  = blockIdx.x >> 8;
    const int n0     = rowgrp * 128 + wv * 32;
    const int mbase  = chunk * 1024;

    HU s0u, s1u;
    s0u.u = srcPK[hd * N_NODES + n0 + r];
    s1u.u = srcPK[hd * N_NODES + n0 + 16 + r];
    const f16x2 se1_0 = { s0u.h[0], s0u.h[0] };
    const f16x2 se5_0 = { s0u.h[1], s0u.h[1] };
    const f16x2 se1_1 = { s1u.h[0], s1u.h[0] };
    const f16x2 se5_1 = { s1u.h[1], s1u.h[1] };

    const f16* e1p = dstE1 + (size_t)hd * N_NODES + mbase;
    const f16* e5p = dstE5 + (size_t)hd * N_NODES + mbase;
    const unsigned char* em0 = emask8 + (size_t)(n0 + r)      * N_NODES + mbase;
    const unsigned char* em1 = emask8 + (size_t)(n0 + 16 + r) * N_NODES + mbase;

    // staging: 4 waves x 16 feat-rows; lane -> (feat = 16wv + lane>>2, m-oct)
    const f16* Vhead = h_t + (size_t)hd * OUT_FEAT * N_NODES + mbase;
    const f16* sbase = Vhead + (size_t)(16 * wv + (lane >> 2)) * N_NODES
                             + (lane & 3) * 8;

    f32x4 acc0 = {}, acc1 = {}, acc2 = {}, acc3 = {}, accD0 = {};
    f32x4 acc4 = {}, acc5 = {}, acc6 = {}, acc7 = {}, accD1 = {};
    f16x8 ones;
    #pragma unroll
    for (int j = 0; j < 8; ++j) ones[j] = (f16)1.0f;

    async_copy16(sbase, &Vs[0][16 * wv * 32]);

    for (int it = 0; it < 32; ++it) {
        const int cur = it & 1;
        __syncthreads();   // drains staged loads for buf[cur]

        {
            int nit = (it + 1) & 31;   // wrap: harmless reload on last iter
            async_copy16(sbase + nit * 32, &Vs[1 - cur][16 * wv * 32]);
        }

        uint4 e1v = *(const uint4*)(e1p + it * 32 + q8);   // 8 f16 E1d
        uint4 e5v = *(const uint4*)(e5p + it * 32 + q8);   // 8 f16 E5d
        uint2 m0v = *(const uint2*)(em0 + it * 32 + q8);   // 8 mask bytes
        uint2 m1v = *(const uint2*)(em1 + it * 32 + q8);

        unsigned e1d[4] = {e1v.x, e1v.y, e1v.z, e1v.w};
        unsigned e5d[4] = {e5v.x, e5v.y, e5v.z, e5v.w};
        unsigned mk0[4], mk1[4];
        mk0[0] = __builtin_amdgcn_perm(0u, m0v.x, 0x01010000u);
        mk0[1] = __builtin_amdgcn_perm(0u, m0v.x, 0x03030202u);
        mk0[2] = __builtin_amdgcn_perm(0u, m0v.y, 0x01010000u);
        mk0[3] = __builtin_amdgcn_perm(0u, m0v.y, 0x03030202u);
        mk1[0] = __builtin_amdgcn_perm(0u, m1v.x, 0x01010000u);
        mk1[1] = __builtin_amdgcn_perm(0u, m1v.x, 0x03030202u);
        mk1[2] = __builtin_amdgcn_perm(0u, m1v.y, 0x01010000u);
        mk1[3] = __builtin_amdgcn_perm(0u, m1v.y, 0x03030202u);

        A8 A0, A1;
        #pragma unroll
        for (int jp = 0; jp < 4; ++jp) {
            HU ed1; ed1.u = e1d[jp];
            HU ed5; ed5.u = e5d[jp];
            HU w0, w1;
            w0.h = __builtin_elementwise_max(se1_0 * ed1.h, se5_0 * ed5.h);
            w1.h = __builtin_elementwise_max(se1_1 * ed1.h, se5_1 * ed5.h);
            A0.u[jp] = w0.u & mk0[jp];
            A1.u[jp] = w1.u & mk1[jp];
        }

        f16x8 b0 = *(const f16x8*)(&Vs[cur][(     r) * 32 + q8]);
        f16x8 b1 = *(const f16x8*)(&Vs[cur][(16 + r) * 32 + q8]);
        f16x8 b2 = *(const f16x8*)(&Vs[cur][(32 + r) * 32 + q8]);
        f16x8 b3 = *(const f16x8*)(&Vs[cur][(48 + r) * 32 + q8]);

        acc0  = __builtin_amdgcn_mfma_f32_16x16x32_f16(A0.v, b0,   acc0,  0, 0, 0);
        acc1  = __builtin_amdgcn_mfma_f32_16x16x32_f16(A0.v, b1,   acc1,  0, 0, 0);
        acc2  = __builtin_amdgcn_mfma_f32_16x16x32_f16(A0.v, b2,   acc2,  0, 0, 0);
        acc3  = __builtin_amdgcn_mfma_f32_16x16x32_f16(A0.v, b3,   acc3,  0, 0, 0);
        accD0 = __builtin_amdgcn_mfma_f32_16x16x32_f16(A0.v, ones, accD0, 0, 0, 0);
        acc4  = __builtin_amdgcn_mfma_f32_16x16x32_f16(A1.v, b0,   acc4,  0, 0, 0);
        acc5  = __builtin_amdgcn_mfma_f32_16x16x32_f16(A1.v, b1,   acc5,  0, 0, 0);
        acc6  = __builtin_amdgcn_mfma_f32_16x16x32_f16(A1.v, b2,   acc6,  0, 0, 0);
        acc7  = __builtin_amdgcn_mfma_f32_16x16x32_f16(A1.v, b3,   acc7,  0, 0, 0);
        accD1 = __builtin_amdgcn_mfma_f32_16x16x32_f16(A1.v, ones, accD1, 0, 0, 0);
    }

    #pragma unroll
    for (int reg = 0; reg < 4; ++reg) {
        int row0 = n0 + 4 * q + reg;
        int row1 = row0 + 16;
        atomicAdd(&numA[((size_t)row0 * NHEAD + hd) * 64 +  0 + r], acc0[reg]);
        atomicAdd(&numA[((size_t)row0 * NHEAD + hd) * 64 + 16 + r], acc1[reg]);
        atomicAdd(&numA[((size_t)row0 * NHEAD + hd) * 64 + 32 + r], acc2[reg]);
        atomicAdd(&numA[((size_t)row0 * NHEAD + hd) * 64 + 48 + r], acc3[reg]);
        atomicAdd(&numA[((size_t)row1 * NHEAD + hd) * 64 +  0 + r], acc4[reg]);
        atomicAdd(&numA[((size_t)row1 * NHEAD + hd) * 64 + 16 + r], acc5[reg]);
        atomicAdd(&numA[((size_t)row1 * NHEAD + hd) * 64 + 32 + r], acc6[reg]);
        atomicAdd(&numA[((size_t)row1 * NHEAD + hd) * 64 + 48 + r], acc7[reg]);
        if (r == 0) {
            atomicAdd(&denA[(size_t)row0 * NHEAD + hd], accD0[reg]);
            atomicAdd(&denA[(size_t)row1 * NHEAD + hd], accD1[reg]);
        }
    }
}

// ---------------------------------------------------------------------------
// Combine: divide, mean over heads, ELU. 256 blocks x 512 thr (2 cols/thr).
// ---------------------------------------------------------------------------
__global__ __launch_bounds__(512) void gat_combine(
    const float* __restrict__ numA,
    const float* __restrict__ denA,
    float* __restrict__ out)
{
    int gid = blockIdx.x * 512 + threadIdx.x;   // 0..131071
    int row = gid >> 5;
    int cp  = (gid & 31) * 2;
    float s0 = 0.f, s1 = 0.f;
    #pragma unroll
    for (int h = 0; h < NHEAD; ++h) {
        float2 v = *(const float2*)(numA + ((size_t)row * NHEAD + h) * 64 + cp);
        float inv = 1.f / denA[(size_t)row * NHEAD + h];
        s0 += v.x * inv;
        s1 += v.y * inv;
    }
    s0 *= 0.125f; s1 *= 0.125f;
    float e0 = s0 > 0.f ? s0 : expm1f(s0);
    float e1 = s1 > 0.f ? s1 : expm1f(s1);
    float2 pk = {e0, e1};
    *(float2*)(out + (size_t)row * OUT_FEAT + cp) = pk;
}

// ---------------------------------------------------------------------------
extern "C" void kernel_launch(void* const* d_in, const int* in_sizes, int n_in,
                              void* d_out, int out_size, void* d_ws, size_t ws_size,
                              hipStream_t stream)
{
    const float* x   = (const float*)d_in[0];
    const int*   adj = (const int*)d_in[1];
    const float* W   = (const float*)d_in[2];
    const float* a   = (const float*)d_in[3];
    float* out = (float*)d_out;

    char* ws = (char*)d_ws;
    f16*           h_t   = (f16*)ws;
    unsigned*      srcPK = (unsigned*)(ws + OFF_SRCPK);
    f16*           dstE1 = (f16*)(ws + OFF_DSTE1);
    f16*           dstE5 = (f16*)(ws + OFF_DSTE5);
    f16*           Wt    = (f16*)(ws + OFF_WT);
    unsigned char* em    = (unsigned char*)(ws + OFF_EM);
    float*         numA  = (float*)(ws + OFF_NUMA);
    float*         denA  = (float*)(ws + OFF_DENA);

    gat_pack   <<<2128, 256, 0, stream>>>(adj, (unsigned*)em, W, Wt, numA);
    gat_phase1 <<<512,  256, 0, stream>>>(x, Wt, a, h_t, srcPK, dstE1, dstE5);
    gat_phase2p<<<1024, 256, 0, stream>>>(h_t, srcPK, dstE1, dstE5, em, numA, denA);
    gat_combine<<<256,  512, 0, stream>>>(numA, denA, out);
}